// Round 5
// baseline (2083.644 us; speedup 1.0000x reference)
//
#include <hip/hip_runtime.h>

// ============================================================================
// Tatt: temp construction (analytic roll-collapse) -> 3x gated GCN (fused-pair
// f16 MFMA GEMM N=768 + banded A-mul + tanh*sigmoid) -> Conv1d(k=577) as
// implicit-im2col f16 MFMA GEMM (split-K=7, atomic reduce) -> bias+transpose.
//
// Dims: B=32, T1=288, T3=864, N=H=325 (pad K->352 "IPAD", pad N->384 "NPAD"),
// KSIZE=577. Conv GEMM: M=9216, N=384(pad), Kflat=577*352=203104 (pad 203136).
//
// R5: k_conv chunk loop 2-phase -> 4-phase (T3/T4/T5). R4 counters showed
// LDS-read (1506 cyc) + MFMA (1863 cyc) = 3448 cyc/chunk observed -> fully
// serialized (m233 2-phase stall). Phase-split staggers waves so the LDS
// stream hides under the MFMA pipe. Also 4Mx2N -> 2Mx4N wave layout
// (wave tile 128x96): 16->14 ds_read/wave/chunk (112 KB/CU, -12%).
// ============================================================================

typedef _Float16 half8 __attribute__((ext_vector_type(8)));
typedef float floatx4 __attribute__((ext_vector_type(4)));

#define DEV __device__ __forceinline__
#define AS1 __attribute__((address_space(1)))
#define AS3 __attribute__((address_space(3)))

constexpr int IPAD = 352;                 // padded inner (sensor) dim
constexpr int NPAD = 384;                 // padded outer (channel) dim
constexpr int NFUSE = 768;                // fused GCN output (two gates)
constexpr int MGCN = 32 * 864;            // 27648
constexpr int MCONV = 32 * 288;           // 9216
constexpr int KCONV_PAD = 203136;         // 3174 * 64  (>= 577*352 = 203104)
constexpr int CONV_SPLITS = 7;
constexpr int CH32_TOTAL = KCONV_PAD / 32;           // 6348
constexpr int CH32_PER = 907;                        // ceil(6348/7); last split 906

// ---- workspace layout (bytes) ----
constexpr size_t OFF_XG = 0;                                   // f16 [27649][352]
constexpr size_t SZ_XG_AL = 19465216;                          // 27649*352*2, aligned
constexpr size_t OFF_S = OFF_XG + SZ_XG_AL;                    // f32 [27648][768] fused
constexpr size_t SZ_S = (size_t)MGCN * NFUSE * 4;              // 84934656
constexpr size_t OFF_WG = OFF_S + SZ_S;                        // 6 * [384][384] f16
constexpr size_t SZ_WG = 6ull * NPAD * NPAD * 2;               // 1769472
constexpr size_t OFF_WCONV = OFF_WG + SZ_WG;                   // [384][203136] f16
constexpr size_t OFF_CPART = OFF_S;                            // alias: f32 [9216][384]
// total = OFF_WCONV + 384*203136*2 = 262,177,792 bytes

DEV void gload16(const void* g, void* l) {
    __builtin_amdgcn_global_load_lds((const AS1 void*)g, (AS3 void*)l, 16, 0, 0);
}

#define MEMFENCE() asm volatile("" ::: "memory")
#define BARRIER() do { MEMFENCE(); __builtin_amdgcn_s_barrier(); MEMFENCE(); } while (0)

// ---------------------------------------------------------------------------
// temp:  Xg[b*864+m][i] = (m in [288,576)) ? IF[b][i][m-288]
//                        : x[(m + s_b + 1728) % 2016][i],   0 for i>=325
// ---------------------------------------------------------------------------
__global__ void k_temp(const float* __restrict__ IF, const float* __restrict__ x,
                       const int* __restrict__ week, const int* __restrict__ hour,
                       _Float16* __restrict__ Xg) {
    int idx = blockIdx.x * 256 + threadIdx.x;       // over 27648*352
    if (idx >= MGCN * IPAD) return;
    int i  = idx % IPAD;
    int mm = idx / IPAD;
    int m  = mm % 864, b = mm / 864;
    float v = 0.f;
    if (i < 325) {
        if (m >= 288 && m < 576) {
            v = IF[((size_t)b * 325 + i) * 288 + (m - 288)];
        } else {
            int s  = week[b] * 288 + hour[b];
            int tm = (m + s + 1728) % 2016;
            v = x[(size_t)tm * 325 + i];
        }
    }
    Xg[(size_t)mm * IPAD + i] = (_Float16)v;
}

// ---------------------------------------------------------------------------
// pack 6 GCN weights, transposed + zero-padded:  Wg[l][o][d] = w_l[d*325+o]
// (pairs 2l,2l+1 are contiguous -> fused GEMM sees one [768][384] B panel)
// ---------------------------------------------------------------------------
__global__ void k_pack_gcn(const float* w0, const float* w1, const float* w2,
                           const float* w3, const float* w4, const float* w5,
                           _Float16* __restrict__ Wg) {
    int idx = blockIdx.x * 256 + threadIdx.x;       // 6*384*384
    int d = idx % NPAD;
    int o = (idx / NPAD) % NPAD;
    int l = idx / (NPAD * NPAD);
    const float* w = l == 0 ? w0 : l == 1 ? w1 : l == 2 ? w2 : l == 3 ? w3 : l == 4 ? w4 : w5;
    float v = (o < 325 && d < 325) ? w[d * 325 + o] : 0.f;
    Wg[(size_t)idx] = (_Float16)v;
}

// ---------------------------------------------------------------------------
// pack conv weights:  Wc[o][k*352+i] = conv_w[o][i][k]  (zero-padded)
// ---------------------------------------------------------------------------
__global__ void k_pack_conv(const float* __restrict__ cw, _Float16* __restrict__ Wc) {
    __shared__ float tile[32][33];
    int o = blockIdx.x, i0 = blockIdx.y * 32, k0 = blockIdx.z * 32;
    int t = threadIdx.x;
    int c = t & 31, r4 = t >> 5;
#pragma unroll
    for (int p = 0; p < 4; ++p) {
        int ii = r4 * 4 + p;
        int i = i0 + ii, k = k0 + c;
        float v = 0.f;
        if (o < 325 && i < 325 && k < 577) v = cw[((size_t)o * 325 + i) * 577 + k];
        tile[ii][c] = v;
    }
    __syncthreads();
#pragma unroll
    for (int p = 0; p < 4; ++p) {
        int kk = r4 * 4 + p;
        int k = k0 + kk, i = i0 + c;
        int kidx = k * IPAD + i;
        if (kidx < KCONV_PAD) Wc[(size_t)o * KCONV_PAD + kidx] = (_Float16)tile[c][kk];
    }
}

// ---------------------------------------------------------------------------
// fused GCN GEMM: 128x128 tile over [27648][768], BK=64 x 6 chunks (K padded
// 384; zero-padded tails contribute 0). global_load_lds + XOR swizzle.
// C[m][n] = sum_K A[m][K] * Bw[n][K], C stride = 768.
// ---------------------------------------------------------------------------
__global__ __launch_bounds__(256) void k_gemm(const _Float16* __restrict__ Xg,
                                              const _Float16* __restrict__ Bw,
                                              float* __restrict__ C) {
    __shared__ _Float16 sA[128 * 64];
    __shared__ _Float16 sB[128 * 64];
    const int t = threadIdx.x;
    const int m0 = blockIdx.x * 128, n0 = blockIdx.y * 128;

    const int rj = t >> 3;
    const int cg = (t & 7) ^ (rj & 7);
    const _Float16* pa[4];
    const _Float16* pb[4];
#pragma unroll
    for (int j = 0; j < 4; ++j) {
        int m = m0 + j * 32 + rj;
        pa[j] = Xg + (size_t)m * IPAD + cg * 8;
        int n = n0 + j * 32 + rj;
        pb[j] = Bw + (size_t)n * NPAD + cg * 8;
    }

    const int lane = t & 63, wv = t >> 6;
    const int wm = wv >> 1, wn = wv & 1;            // 2x2 waves of 64x64
    const int r = lane & 15, q = lane >> 4, s8 = r & 7;
    int aRow[4], bRow[4];
#pragma unroll
    for (int i = 0; i < 4; ++i) {
        aRow[i] = (wm * 64 + i * 16 + r) * 64;
        bRow[i] = (wn * 64 + i * 16 + r) * 64;
    }
    const int xk0 = (q ^ s8) * 8;
    const int xk1 = ((q + 4) ^ s8) * 8;

    floatx4 acc[4][4] = {};

    for (int ch = 0; ch < 6; ++ch) {
        __syncthreads();
#pragma unroll
        for (int j = 0; j < 4; ++j) { gload16(pa[j], &sA[(j * 256 + t) * 8]); pa[j] += 64; }
#pragma unroll
        for (int j = 0; j < 4; ++j) { gload16(pb[j], &sB[(j * 256 + t) * 8]); pb[j] += 64; }
        __syncthreads();
#pragma unroll
        for (int kk = 0; kk < 2; ++kk) {
            const int xk = kk ? xk1 : xk0;
            half8 av[4], bv[4];
#pragma unroll
            for (int mi = 0; mi < 4; ++mi) av[mi] = *(const half8*)(sA + aRow[mi] + xk);
#pragma unroll
            for (int ni = 0; ni < 4; ++ni) bv[ni] = *(const half8*)(sB + bRow[ni] + xk);
#pragma unroll
            for (int mi = 0; mi < 4; ++mi)
#pragma unroll
                for (int ni = 0; ni < 4; ++ni)
                    acc[mi][ni] = __builtin_amdgcn_mfma_f32_16x16x32_f16(av[mi], bv[ni],
                                                                         acc[mi][ni], 0, 0, 0);
        }
    }

    // C/D layout: col = lane&15, row = (lane>>4)*4 + reg   [m89-verified]
#pragma unroll
    for (int mi = 0; mi < 4; ++mi)
#pragma unroll
        for (int ni = 0; ni < 4; ++ni) {
            int row = m0 + wm * 64 + mi * 16 + q * 4;
            int col = n0 + wn * 64 + ni * 16 + r;
#pragma unroll
            for (int e = 0; e < 4; ++e)
                C[(size_t)(row + e) * NFUSE + col] = acc[mi][ni][e];
        }
}

// ---------------------------------------------------------------------------
// conv GEMM: 256x384 tile (full N), BK=32, 512 threads = 8 waves, 2M x 4N
// (wave tile 128x96). Triple-buffered LDS (3 x 40 KB), depth-2 prefetch with
// counted s_waitcnt vmcnt(10). 4-phase MFMA schedule: bv[0..5] + av-pair per
// phase; {reads -> barrier -> lgkmcnt(0) -> setprio(1) -> 12 MFMA}. Phase-p
// reads issue while other waves finish phase p-1 MFMA -> LDS stream hides
// under the MFMA pipe (was fully serialized: 1863+1506 cyc/chunk, R4).
// Split-K=7 (252 blocks); partials via HW f32 atomics into zeroed buffer.
//
// LDS layout per buffer: A = 128 "pair-lines" (rows 2j,2j+1; 8 x 16B blocks,
// 128 B/line) then B = 192 pair-lines. Slot (j,cc) holds global block
// g = cc ^ (j&7), g = (rowparity<<2)|kblk. Frag reads: stepping 16 rows = 8
// lines keeps (row>>1)&7 -> offset = base + idx*1024; 2-way bank aliasing
// max (free, m136). LDS dest is wave-uniform base + lane*16 (m104-safe).
// Buffer safety: final barrier per chunk ensures all reads of buf done
// before any wave (at chunk c+2) stages into it again.
// ---------------------------------------------------------------------------
__global__ __launch_bounds__(512, 2) void k_conv(const _Float16* __restrict__ Xg,
                                                 const _Float16* __restrict__ Wc,
                                                 float* __restrict__ C) {
    __shared__ _Float16 lds[3 * 20480];             // 3 x 40960 B = 122880 B
    const int t = threadIdx.x;
    const int m0 = blockIdx.x * 256;
    const int chunk0 = blockIdx.y * CH32_PER;
    int nch = CH32_TOTAL - chunk0;
    if (nch > CH32_PER) nch = CH32_PER;             // last split: 906

    // ---- staging: 5 slots/thread (2 A + 3 B) ----
    const _Float16* src[5];
    int ldsoff[5];                                  // byte offset within a buffer
#pragma unroll
    for (int p = 0; p < 2; ++p) {
        int s = t + p * 512;                        // A slot 0..1023
        int j = s >> 3, cc = s & 7;
        int g = cc ^ (j & 7);
        int m = m0 + 2 * j + (g >> 2);
        int mrow = m + (m / 288) * 576;             // implicit im2col
        src[p] = Xg + (size_t)mrow * IPAD + (size_t)chunk0 * 32 + (g & 3) * 8;
        ldsoff[p] = s * 16;
    }
#pragma unroll
    for (int p = 0; p < 3; ++p) {
        int s = t + p * 512;                        // B slot 0..1535
        int j = s >> 3, cc = s & 7;
        int g = cc ^ (j & 7);
        int n = 2 * j + (g >> 2);
        src[2 + p] = Wc + (size_t)n * KCONV_PAD + (size_t)chunk0 * 32 + (g & 3) * 8;
        ldsoff[2 + p] = 16384 + s * 16;
    }

    // ---- fragment read offsets (2M x 4N) ----
    const int lane = t & 63, wv = t >> 6;
    const int wm = wv >> 2, wn = wv & 3;
    const int r = lane & 15, q = lane >> 4;
    int row_a = wm * 128 + r;
    int aoff0 = (row_a >> 1) * 128 + ((((row_a & 1) << 2) | q) ^ ((row_a >> 1) & 7)) * 16;
    int row_b = wn * 96 + r;
    int boff0 = 16384 + (row_b >> 1) * 128 +
                ((((row_b & 1) << 2) | q) ^ ((row_b >> 1) & 7)) * 16;

    floatx4 acc[8][6] = {};

    auto stage = [&](int lc, int buf) {
        char* dst = (char*)lds + buf * 40960;
        size_t adv = (size_t)lc * 32;               // 32 halfs = 64 B per chunk
#pragma unroll
        for (int p = 0; p < 5; ++p)
            gload16(src[p] + adv, dst + ldsoff[p]);
    };

    // prologue: chunks 0,1 in flight
    stage(0, 0);
    stage(1, 1);

    int buf = 0;
    for (int lc = 0; lc < nch; ++lc) {
        int pre = lc + 2;  if (pre > nch - 1) pre = nch - 1;     // tail: dummy re-read
        int pbuf = buf + 2; if (pbuf >= 3) pbuf -= 3;
        stage(pre, pbuf);                            // issue loads for lc+2
        asm volatile("s_waitcnt vmcnt(10)" ::: "memory");        // chunk lc landed
        BARRIER();                                   // buf data visible to all
        const char* cb = (const char*)lds + buf * 40960;

        // ---- phase 0: read all 6 bv + av pair 0, then 12 MFMA ----
        half8 bv[6];
#pragma unroll
        for (int ni = 0; ni < 6; ++ni)
            bv[ni] = *(const half8*)(cb + boff0 + ni * 1024);
        half8 av0 = *(const half8*)(cb + aoff0);
        half8 av1 = *(const half8*)(cb + aoff0 + 1024);
        BARRIER();
        asm volatile("s_waitcnt lgkmcnt(0)" ::: "memory");
        __builtin_amdgcn_sched_barrier(0);
        __builtin_amdgcn_s_setprio(1);
#pragma unroll
        for (int ni = 0; ni < 6; ++ni) {
            acc[0][ni] = __builtin_amdgcn_mfma_f32_16x16x32_f16(av0, bv[ni], acc[0][ni], 0, 0, 0);
            acc[1][ni] = __builtin_amdgcn_mfma_f32_16x16x32_f16(av1, bv[ni], acc[1][ni], 0, 0, 0);
        }
        __builtin_amdgcn_s_setprio(0);

        // ---- phases 1..3: read av pair p, 12 MFMA ----
#pragma unroll
        for (int p = 1; p < 4; ++p) {
            half8 a0 = *(const half8*)(cb + aoff0 + (2 * p) * 1024);
            half8 a1 = *(const half8*)(cb + aoff0 + (2 * p + 1) * 1024);
            BARRIER();
            asm volatile("s_waitcnt lgkmcnt(0)" ::: "memory");
            __builtin_amdgcn_sched_barrier(0);
            __builtin_amdgcn_s_setprio(1);
#pragma unroll
            for (int ni = 0; ni < 6; ++ni) {
                acc[2 * p][ni] =
                    __builtin_amdgcn_mfma_f32_16x16x32_f16(a0, bv[ni], acc[2 * p][ni], 0, 0, 0);
                acc[2 * p + 1][ni] =
                    __builtin_amdgcn_mfma_f32_16x16x32_f16(a1, bv[ni], acc[2 * p + 1][ni], 0, 0, 0);
            }
            __builtin_amdgcn_s_setprio(0);
        }

        BARRIER();                                   // all reads of buf done
        buf = (buf + 1 == 3) ? 0 : buf + 1;
    }
    asm volatile("s_waitcnt vmcnt(0)" ::: "memory");

    // C/D layout: col = lane&15, row = (lane>>4)*4 + reg   [m89-verified]
    // HW f32 atomic add (unsafeAtomicAdd -> global_atomic_add_f32)
#pragma unroll
    for (int mi = 0; mi < 8; ++mi)
#pragma unroll
        for (int ni = 0; ni < 6; ++ni) {
            int row = m0 + wm * 128 + mi * 16 + q * 4;
            int col = wn * 96 + ni * 16 + r;
#pragma unroll
            for (int e = 0; e < 4; ++e)
                unsafeAtomicAdd(&C[(size_t)(row + e) * NPAD + col], acc[mi][ni][e]);
        }
}

// ---------------------------------------------------------------------------
// banded D^-1/2 A D^-1/2 (7-diag) + bias + tanh*sigmoid -> f16 Xg (in place)
// Fused S layout: S[m][0..383] = gate1 (tanh), S[m][384..767] = gate2 (sigm).
// ---------------------------------------------------------------------------
__global__ void k_bandact(const float* __restrict__ S,
                          const float* __restrict__ b1, const float* __restrict__ b2,
                          _Float16* __restrict__ Xg) {
    int bm = blockIdx.x;                            // 0..27647
    int m = bm % 864;
    int dm = (m < 3 ? m : 3) + ((863 - m) < 3 ? (863 - m) : 3) + 1;
    for (int o = threadIdx.x; o < 325; o += 256) {
        float g1 = b1[o], g2 = b2[o];
#pragma unroll
        for (int dn = -3; dn <= 3; ++dn) {
            int n = m + dn;
            if (n < 0 || n > 863) continue;
            int dnd = (n < 3 ? n : 3) + ((863 - n) < 3 ? (863 - n) : 3) + 1;
            float a = rsqrtf((float)(dm * dnd));
            size_t off = (size_t)(bm + dn) * NFUSE + o;
            g1 += a * S[off];
            g2 += a * S[off + NPAD];
        }
        float vt = tanhf(g1);
        float vs = 1.f / (1.f + expf(-g2));
        Xg[(size_t)bm * IPAD + o] = (_Float16)(vt * vs);
    }
}

// ---------------------------------------------------------------------------
// conv bias + transpose [m=(b,t)][o] -> out[b][o][t]
// ---------------------------------------------------------------------------
__global__ void k_reduce(const float* __restrict__ Cp, const float* __restrict__ cb,
                         float* __restrict__ out) {
    __shared__ float tile[32][33];
    int b = blockIdx.x, t0 = blockIdx.y * 32, o0 = blockIdx.z * 32;
    int t = threadIdx.x;
    int c = t & 31, r4 = t >> 5;
#pragma unroll
    for (int p = 0; p < 4; ++p) {
        int tt = r4 * 4 + p;
        tile[tt][c] = Cp[(size_t)(b * 288 + t0 + tt) * NPAD + (o0 + c)];
    }
    __syncthreads();
#pragma unroll
    for (int p = 0; p < 4; ++p) {
        int oo = r4 * 4 + p;
        int o = o0 + oo;
        if (o < 325)
            out[((size_t)b * 325 + o) * 288 + t0 + c] = tile[c][oo] + cb[o];
    }
}

// ---------------------------------------------------------------------------
extern "C" void kernel_launch(void* const* d_in, const int* in_sizes, int n_in,
                              void* d_out, int out_size, void* d_ws, size_t ws_size,
                              hipStream_t stream) {
    const float* IF = (const float*)d_in[0];
    const float* x  = (const float*)d_in[1];
    const float* wg[6] = {(const float*)d_in[2],  (const float*)d_in[4],
                          (const float*)d_in[6],  (const float*)d_in[8],
                          (const float*)d_in[10], (const float*)d_in[12]};
    const float* bg[6] = {(const float*)d_in[3],  (const float*)d_in[5],
                          (const float*)d_in[7],  (const float*)d_in[9],
                          (const float*)d_in[11], (const float*)d_in[13]};
    const float* cw  = (const float*)d_in[14];
    const float* cb  = (const float*)d_in[15];
    const int* week  = (const int*)d_in[16];
    const int* hour  = (const int*)d_in[17];
    float* out = (float*)d_out;

    char* ws = (char*)d_ws;
    _Float16* Xg = (_Float16*)(ws + OFF_XG);
    float* S     = (float*)(ws + OFF_S);
    _Float16* Wg = (_Float16*)(ws + OFF_WG);
    _Float16* Wc = (_Float16*)(ws + OFF_WCONV);
    float* Cp    = (float*)(ws + OFF_CPART);   // aliases S (conv phase only)

    k_pack_gcn<<<(6 * NPAD * NPAD) / 256, 256, 0, stream>>>(wg[0], wg[1], wg[2], wg[3],
                                                            wg[4], wg[5], Wg);
    k_pack_conv<<<dim3(NPAD, 11, 19), 256, 0, stream>>>(cw, Wc);
    k_temp<<<(MGCN * IPAD) / 256, 256, 0, stream>>>(IF, x, week, hour, Xg);

    for (int l = 0; l < 3; ++l) {
        k_gemm<<<dim3(MGCN / 128, NFUSE / 128), 256, 0, stream>>>(
            Xg, Wg + (size_t)(2 * l) * NPAD * NPAD, S);
        k_bandact<<<MGCN, 256, 0, stream>>>(S, bg[2 * l], bg[2 * l + 1], Xg);
    }

    hipMemsetAsync(Cp, 0, (size_t)MCONV * NPAD * 4, stream);
    k_conv<<<dim3(MCONV / 256, CONV_SPLITS), 512, 0, stream>>>(Xg, Wc, Cp);

    k_reduce<<<dim3(32, 9, 11), 256, 0, stream>>>(Cp, cb, out);
}

// Round 6
// 2051.769 us; speedup vs baseline: 1.0155x; 1.0155x over previous
//
#include <hip/hip_runtime.h>

// ============================================================================
// Tatt: temp construction (analytic roll-collapse) -> 3x gated GCN (fused-pair
// f16 MFMA GEMM N=768 + banded A-mul + tanh*sigmoid) -> Conv1d(k=577) as
// implicit-im2col f16 MFMA GEMM (split-K=7, atomic reduce) -> bias+transpose.
//
// Dims: B=32, T1=288, T3=864, N=H=325 (pad K->352 "IPAD", pad N->384 "NPAD"),
// KSIZE=577. Conv GEMM: M=9216, N=384(pad), Kflat=577*352=203104 (pad 203136).
//
// R6: k_conv back to 2 barriers/chunk; chunk body software-pipelined AITER-
// style: counted lgkmcnt(2) batches interleave each av-pair's 12 MFMA with
// the next pair's ds_reads. R4/R5 were strictly additive (MFMA 1863 + LDS
// 1318 cyc/chunk): all reads drained before first MFMA. Counted lgkm waits +
// sched_barrier(0) after each (hipcc hoists reg-only MFMA past asm waits)
// let the LDS stream hide under the MFMA pipe within each wave.
// ============================================================================

typedef _Float16 half8 __attribute__((ext_vector_type(8)));
typedef float floatx4 __attribute__((ext_vector_type(4)));

#define DEV __device__ __forceinline__
#define AS1 __attribute__((address_space(1)))
#define AS3 __attribute__((address_space(3)))

constexpr int IPAD = 352;                 // padded inner (sensor) dim
constexpr int NPAD = 384;                 // padded outer (channel) dim
constexpr int NFUSE = 768;                // fused GCN output (two gates)
constexpr int MGCN = 32 * 864;            // 27648
constexpr int MCONV = 32 * 288;           // 9216
constexpr int KCONV_PAD = 203136;         // 3174 * 64  (>= 577*352 = 203104)
constexpr int CONV_SPLITS = 7;
constexpr int CH32_TOTAL = KCONV_PAD / 32;           // 6348
constexpr int CH32_PER = 907;                        // ceil(6348/7); last split 906

// ---- workspace layout (bytes) ----
constexpr size_t OFF_XG = 0;                                   // f16 [27649][352]
constexpr size_t SZ_XG_AL = 19465216;                          // 27649*352*2, aligned
constexpr size_t OFF_S = OFF_XG + SZ_XG_AL;                    // f32 [27648][768] fused
constexpr size_t SZ_S = (size_t)MGCN * NFUSE * 4;              // 84934656
constexpr size_t OFF_WG = OFF_S + SZ_S;                        // 6 * [384][384] f16
constexpr size_t SZ_WG = 6ull * NPAD * NPAD * 2;               // 1769472
constexpr size_t OFF_WCONV = OFF_WG + SZ_WG;                   // [384][203136] f16
constexpr size_t OFF_CPART = OFF_S;                            // alias: f32 [9216][384]
// total = OFF_WCONV + 384*203136*2 = 262,177,792 bytes

DEV void gload16(const void* g, void* l) {
    __builtin_amdgcn_global_load_lds((const AS1 void*)g, (AS3 void*)l, 16, 0, 0);
}

#define MEMFENCE() asm volatile("" ::: "memory")
#define BARRIER() do { MEMFENCE(); __builtin_amdgcn_s_barrier(); MEMFENCE(); } while (0)
#define MFMA16(a, b, c) __builtin_amdgcn_mfma_f32_16x16x32_f16((a), (b), (c), 0, 0, 0)

// ---------------------------------------------------------------------------
// temp:  Xg[b*864+m][i] = (m in [288,576)) ? IF[b][i][m-288]
//                        : x[(m + s_b + 1728) % 2016][i],   0 for i>=325
// ---------------------------------------------------------------------------
__global__ void k_temp(const float* __restrict__ IF, const float* __restrict__ x,
                       const int* __restrict__ week, const int* __restrict__ hour,
                       _Float16* __restrict__ Xg) {
    int idx = blockIdx.x * 256 + threadIdx.x;       // over 27648*352
    if (idx >= MGCN * IPAD) return;
    int i  = idx % IPAD;
    int mm = idx / IPAD;
    int m  = mm % 864, b = mm / 864;
    float v = 0.f;
    if (i < 325) {
        if (m >= 288 && m < 576) {
            v = IF[((size_t)b * 325 + i) * 288 + (m - 288)];
        } else {
            int s  = week[b] * 288 + hour[b];
            int tm = (m + s + 1728) % 2016;
            v = x[(size_t)tm * 325 + i];
        }
    }
    Xg[(size_t)mm * IPAD + i] = (_Float16)v;
}

// ---------------------------------------------------------------------------
// pack 6 GCN weights, transposed + zero-padded:  Wg[l][o][d] = w_l[d*325+o]
// (pairs 2l,2l+1 are contiguous -> fused GEMM sees one [768][384] B panel)
// ---------------------------------------------------------------------------
__global__ void k_pack_gcn(const float* w0, const float* w1, const float* w2,
                           const float* w3, const float* w4, const float* w5,
                           _Float16* __restrict__ Wg) {
    int idx = blockIdx.x * 256 + threadIdx.x;       // 6*384*384
    int d = idx % NPAD;
    int o = (idx / NPAD) % NPAD;
    int l = idx / (NPAD * NPAD);
    const float* w = l == 0 ? w0 : l == 1 ? w1 : l == 2 ? w2 : l == 3 ? w3 : l == 4 ? w4 : w5;
    float v = (o < 325 && d < 325) ? w[d * 325 + o] : 0.f;
    Wg[(size_t)idx] = (_Float16)v;
}

// ---------------------------------------------------------------------------
// pack conv weights:  Wc[o][k*352+i] = conv_w[o][i][k]  (zero-padded)
// ---------------------------------------------------------------------------
__global__ void k_pack_conv(const float* __restrict__ cw, _Float16* __restrict__ Wc) {
    __shared__ float tile[32][33];
    int o = blockIdx.x, i0 = blockIdx.y * 32, k0 = blockIdx.z * 32;
    int t = threadIdx.x;
    int c = t & 31, r4 = t >> 5;
#pragma unroll
    for (int p = 0; p < 4; ++p) {
        int ii = r4 * 4 + p;
        int i = i0 + ii, k = k0 + c;
        float v = 0.f;
        if (o < 325 && i < 325 && k < 577) v = cw[((size_t)o * 325 + i) * 577 + k];
        tile[ii][c] = v;
    }
    __syncthreads();
#pragma unroll
    for (int p = 0; p < 4; ++p) {
        int kk = r4 * 4 + p;
        int k = k0 + kk, i = i0 + c;
        int kidx = k * IPAD + i;
        if (kidx < KCONV_PAD) Wc[(size_t)o * KCONV_PAD + kidx] = (_Float16)tile[c][kk];
    }
}

// ---------------------------------------------------------------------------
// fused GCN GEMM: 128x128 tile over [27648][768], BK=64 x 6 chunks (K padded
// 384; zero-padded tails contribute 0). global_load_lds + XOR swizzle.
// C[m][n] = sum_K A[m][K] * Bw[n][K], C stride = 768.
// ---------------------------------------------------------------------------
__global__ __launch_bounds__(256) void k_gemm(const _Float16* __restrict__ Xg,
                                              const _Float16* __restrict__ Bw,
                                              float* __restrict__ C) {
    __shared__ _Float16 sA[128 * 64];
    __shared__ _Float16 sB[128 * 64];
    const int t = threadIdx.x;
    const int m0 = blockIdx.x * 128, n0 = blockIdx.y * 128;

    const int rj = t >> 3;
    const int cg = (t & 7) ^ (rj & 7);
    const _Float16* pa[4];
    const _Float16* pb[4];
#pragma unroll
    for (int j = 0; j < 4; ++j) {
        int m = m0 + j * 32 + rj;
        pa[j] = Xg + (size_t)m * IPAD + cg * 8;
        int n = n0 + j * 32 + rj;
        pb[j] = Bw + (size_t)n * NPAD + cg * 8;
    }

    const int lane = t & 63, wv = t >> 6;
    const int wm = wv >> 1, wn = wv & 1;            // 2x2 waves of 64x64
    const int r = lane & 15, q = lane >> 4, s8 = r & 7;
    int aRow[4], bRow[4];
#pragma unroll
    for (int i = 0; i < 4; ++i) {
        aRow[i] = (wm * 64 + i * 16 + r) * 64;
        bRow[i] = (wn * 64 + i * 16 + r) * 64;
    }
    const int xk0 = (q ^ s8) * 8;
    const int xk1 = ((q + 4) ^ s8) * 8;

    floatx4 acc[4][4] = {};

    for (int ch = 0; ch < 6; ++ch) {
        __syncthreads();
#pragma unroll
        for (int j = 0; j < 4; ++j) { gload16(pa[j], &sA[(j * 256 + t) * 8]); pa[j] += 64; }
#pragma unroll
        for (int j = 0; j < 4; ++j) { gload16(pb[j], &sB[(j * 256 + t) * 8]); pb[j] += 64; }
        __syncthreads();
#pragma unroll
        for (int kk = 0; kk < 2; ++kk) {
            const int xk = kk ? xk1 : xk0;
            half8 av[4], bv[4];
#pragma unroll
            for (int mi = 0; mi < 4; ++mi) av[mi] = *(const half8*)(sA + aRow[mi] + xk);
#pragma unroll
            for (int ni = 0; ni < 4; ++ni) bv[ni] = *(const half8*)(sB + bRow[ni] + xk);
#pragma unroll
            for (int mi = 0; mi < 4; ++mi)
#pragma unroll
                for (int ni = 0; ni < 4; ++ni)
                    acc[mi][ni] = MFMA16(av[mi], bv[ni], acc[mi][ni]);
        }
    }

    // C/D layout: col = lane&15, row = (lane>>4)*4 + reg   [m89-verified]
#pragma unroll
    for (int mi = 0; mi < 4; ++mi)
#pragma unroll
        for (int ni = 0; ni < 4; ++ni) {
            int row = m0 + wm * 64 + mi * 16 + q * 4;
            int col = n0 + wn * 64 + ni * 16 + r;
#pragma unroll
            for (int e = 0; e < 4; ++e)
                C[(size_t)(row + e) * NFUSE + col] = acc[mi][ni][e];
        }
}

// ---------------------------------------------------------------------------
// conv GEMM: 256x384 tile (full N), BK=32, 512 threads = 8 waves, 2M x 4N
// (wave tile 128x96). Triple-buffered LDS (3 x 40 KB), depth-2 global
// prefetch with counted s_waitcnt vmcnt(10). Chunk body is software-
// pipelined: {bv0..5,a0,a1} + prefetch {a2,a3}; then 4 batches of 12 MFMA,
// each gated by lgkmcnt(2) with the NEXT av-pair's ds_reads issued inside
// the previous batch. sched_barrier(0) after each asm wait (rule #18).
// MEMFENCE after group 1 pins lgkm retirement order (in-order retire ->
// lgkmcnt(2) == "all of group 1 landed").
// Split-K=7 (252 blocks); partials via HW f32 atomics into zeroed buffer.
//
// LDS layout per buffer: A = 128 "pair-lines" (rows 2j,2j+1; 8 x 16B blocks,
// 128 B/line) then B = 192 pair-lines. Slot (j,cc) holds global block
// g = cc ^ (j&7), g = (rowparity<<2)|kblk. Frag reads: stepping 16 rows = 8
// lines keeps (row>>1)&7 -> offset = base + idx*1024; 2-way bank aliasing
// max (free, m136). LDS dest is wave-uniform base + lane*16 (m104-safe).
// Buffer safety: end barrier per chunk ensures all reads of buf done
// before any wave (at chunk c+2) stages into it again.
// ---------------------------------------------------------------------------
__global__ __launch_bounds__(512, 2) void k_conv(const _Float16* __restrict__ Xg,
                                                 const _Float16* __restrict__ Wc,
                                                 float* __restrict__ C) {
    __shared__ _Float16 lds[3 * 20480];             // 3 x 40960 B = 122880 B
    const int t = threadIdx.x;
    const int m0 = blockIdx.x * 256;
    const int chunk0 = blockIdx.y * CH32_PER;
    int nch = CH32_TOTAL - chunk0;
    if (nch > CH32_PER) nch = CH32_PER;             // last split: 906

    // ---- staging: 5 slots/thread (2 A + 3 B) ----
    const _Float16* src[5];
    int ldsoff[5];                                  // byte offset within a buffer
#pragma unroll
    for (int p = 0; p < 2; ++p) {
        int s = t + p * 512;                        // A slot 0..1023
        int j = s >> 3, cc = s & 7;
        int g = cc ^ (j & 7);
        int m = m0 + 2 * j + (g >> 2);
        int mrow = m + (m / 288) * 576;             // implicit im2col
        src[p] = Xg + (size_t)mrow * IPAD + (size_t)chunk0 * 32 + (g & 3) * 8;
        ldsoff[p] = s * 16;
    }
#pragma unroll
    for (int p = 0; p < 3; ++p) {
        int s = t + p * 512;                        // B slot 0..1535
        int j = s >> 3, cc = s & 7;
        int g = cc ^ (j & 7);
        int n = 2 * j + (g >> 2);
        src[2 + p] = Wc + (size_t)n * KCONV_PAD + (size_t)chunk0 * 32 + (g & 3) * 8;
        ldsoff[2 + p] = 16384 + s * 16;
    }

    // ---- fragment read offsets (2M x 4N) ----
    const int lane = t & 63, wv = t >> 6;
    const int wm = wv >> 2, wn = wv & 3;
    const int r = lane & 15, q = lane >> 4;
    int row_a = wm * 128 + r;
    int aoff0 = (row_a >> 1) * 128 + ((((row_a & 1) << 2) | q) ^ ((row_a >> 1) & 7)) * 16;
    int row_b = wn * 96 + r;
    int boff0 = 16384 + (row_b >> 1) * 128 +
                ((((row_b & 1) << 2) | q) ^ ((row_b >> 1) & 7)) * 16;

    floatx4 acc[8][6] = {};

    auto stage = [&](int lc, int buf) {
        char* dst = (char*)lds + buf * 40960;
        size_t adv = (size_t)lc * 32;               // 32 halfs = 64 B per chunk
#pragma unroll
        for (int p = 0; p < 5; ++p)
            gload16(src[p] + adv, dst + ldsoff[p]);
    };

    // prologue: chunks 0,1 in flight
    stage(0, 0);
    stage(1, 1);

    int buf = 0;
    for (int lc = 0; lc < nch; ++lc) {
        int pre = lc + 2;  if (pre > nch - 1) pre = nch - 1;     // tail: dummy re-read
        int pbuf = buf + 2; if (pbuf >= 3) pbuf -= 3;
        stage(pre, pbuf);                            // issue loads for lc+2
        asm volatile("s_waitcnt vmcnt(10)" ::: "memory");        // chunk lc landed
        BARRIER();                                   // buf data visible to all
        const char* cb = (const char*)lds + buf * 40960;

        // group 1: bv0..5 + a0,a1 (the 8 oldest lgkm ops after the fence)
        half8 bv[6];
#pragma unroll
        for (int ni = 0; ni < 6; ++ni)
            bv[ni] = *(const half8*)(cb + boff0 + ni * 1024);
        half8 a0 = *(const half8*)(cb + aoff0);
        half8 a1 = *(const half8*)(cb + aoff0 + 1024);
        MEMFENCE();                                  // pin age order for lgkm counts
        half8 a2 = *(const half8*)(cb + aoff0 + 2048);
        half8 a3 = *(const half8*)(cb + aoff0 + 3072);

        asm volatile("s_waitcnt lgkmcnt(2)" ::: "memory");  // group1 landed; a2,a3 in flight
        __builtin_amdgcn_sched_barrier(0);
        __builtin_amdgcn_s_setprio(1);
#pragma unroll
        for (int ni = 0; ni < 6; ++ni) {
            acc[0][ni] = MFMA16(a0, bv[ni], acc[0][ni]);
            acc[1][ni] = MFMA16(a1, bv[ni], acc[1][ni]);
        }
        half8 a4 = *(const half8*)(cb + aoff0 + 4096);
        half8 a5 = *(const half8*)(cb + aoff0 + 5120);
        asm volatile("s_waitcnt lgkmcnt(2)" ::: "memory");  // a2,a3 landed
        __builtin_amdgcn_sched_barrier(0);
#pragma unroll
        for (int ni = 0; ni < 6; ++ni) {
            acc[2][ni] = MFMA16(a2, bv[ni], acc[2][ni]);
            acc[3][ni] = MFMA16(a3, bv[ni], acc[3][ni]);
        }
        half8 a6 = *(const half8*)(cb + aoff0 + 6144);
        half8 a7 = *(const half8*)(cb + aoff0 + 7168);
        asm volatile("s_waitcnt lgkmcnt(2)" ::: "memory");  // a4,a5 landed
        __builtin_amdgcn_sched_barrier(0);
#pragma unroll
        for (int ni = 0; ni < 6; ++ni) {
            acc[4][ni] = MFMA16(a4, bv[ni], acc[4][ni]);
            acc[5][ni] = MFMA16(a5, bv[ni], acc[5][ni]);
        }
        asm volatile("s_waitcnt lgkmcnt(0)" ::: "memory");  // a6,a7 landed
        __builtin_amdgcn_sched_barrier(0);
#pragma unroll
        for (int ni = 0; ni < 6; ++ni) {
            acc[6][ni] = MFMA16(a6, bv[ni], acc[6][ni]);
            acc[7][ni] = MFMA16(a7, bv[ni], acc[7][ni]);
        }
        __builtin_amdgcn_s_setprio(0);

        BARRIER();                                   // all reads of buf done
        buf = (buf + 1 == 3) ? 0 : buf + 1;
    }
    asm volatile("s_waitcnt vmcnt(0)" ::: "memory");

    // C/D layout: col = lane&15, row = (lane>>4)*4 + reg   [m89-verified]
    // HW f32 atomic add (unsafeAtomicAdd -> global_atomic_add_f32)
#pragma unroll
    for (int mi = 0; mi < 8; ++mi)
#pragma unroll
        for (int ni = 0; ni < 6; ++ni) {
            int row = m0 + wm * 128 + mi * 16 + q * 4;
            int col = wn * 96 + ni * 16 + r;
#pragma unroll
            for (int e = 0; e < 4; ++e)
                unsafeAtomicAdd(&C[(size_t)(row + e) * NPAD + col], acc[mi][ni][e]);
        }
}

// ---------------------------------------------------------------------------
// banded D^-1/2 A D^-1/2 (7-diag) + bias + tanh*sigmoid -> f16 Xg (in place)
// Fused S layout: S[m][0..383] = gate1 (tanh), S[m][384..767] = gate2 (sigm).
// ---------------------------------------------------------------------------
__global__ void k_bandact(const float* __restrict__ S,
                          const float* __restrict__ b1, const float* __restrict__ b2,
                          _Float16* __restrict__ Xg) {
    int bm = blockIdx.x;                            // 0..27647
    int m = bm % 864;
    int dm = (m < 3 ? m : 3) + ((863 - m) < 3 ? (863 - m) : 3) + 1;
    for (int o = threadIdx.x; o < 325; o += 256) {
        float g1 = b1[o], g2 = b2[o];
#pragma unroll
        for (int dn = -3; dn <= 3; ++dn) {
            int n = m + dn;
            if (n < 0 || n > 863) continue;
            int dnd = (n < 3 ? n : 3) + ((863 - n) < 3 ? (863 - n) : 3) + 1;
            float a = rsqrtf((float)(dm * dnd));
            size_t off = (size_t)(bm + dn) * NFUSE + o;
            g1 += a * S[off];
            g2 += a * S[off + NPAD];
        }
        float vt = tanhf(g1);
        float vs = 1.f / (1.f + expf(-g2));
        Xg[(size_t)bm * IPAD + o] = (_Float16)(vt * vs);
    }
}

// ---------------------------------------------------------------------------
// conv bias + transpose [m=(b,t)][o] -> out[b][o][t]
// ---------------------------------------------------------------------------
__global__ void k_reduce(const float* __restrict__ Cp, const float* __restrict__ cb,
                         float* __restrict__ out) {
    __shared__ float tile[32][33];
    int b = blockIdx.x, t0 = blockIdx.y * 32, o0 = blockIdx.z * 32;
    int t = threadIdx.x;
    int c = t & 31, r4 = t >> 5;
#pragma unroll
    for (int p = 0; p < 4; ++p) {
        int tt = r4 * 4 + p;
        tile[tt][c] = Cp[(size_t)(b * 288 + t0 + tt) * NPAD + (o0 + c)];
    }
    __syncthreads();
#pragma unroll
    for (int p = 0; p < 4; ++p) {
        int oo = r4 * 4 + p;
        int o = o0 + oo;
        if (o < 325)
            out[((size_t)b * 325 + o) * 288 + t0 + c] = tile[c][oo] + cb[o];
    }
}

// ---------------------------------------------------------------------------
extern "C" void kernel_launch(void* const* d_in, const int* in_sizes, int n_in,
                              void* d_out, int out_size, void* d_ws, size_t ws_size,
                              hipStream_t stream) {
    const float* IF = (const float*)d_in[0];
    const float* x  = (const float*)d_in[1];
    const float* wg[6] = {(const float*)d_in[2],  (const float*)d_in[4],
                          (const float*)d_in[6],  (const float*)d_in[8],
                          (const float*)d_in[10], (const float*)d_in[12]};
    const float* bg[6] = {(const float*)d_in[3],  (const float*)d_in[5],
                          (const float*)d_in[7],  (const float*)d_in[9],
                          (const float*)d_in[11], (const float*)d_in[13]};
    const float* cw  = (const float*)d_in[14];
    const float* cb  = (const float*)d_in[15];
    const int* week  = (const int*)d_in[16];
    const int* hour  = (const int*)d_in[17];
    float* out = (float*)d_out;

    char* ws = (char*)d_ws;
    _Float16* Xg = (_Float16*)(ws + OFF_XG);
    float* S     = (float*)(ws + OFF_S);
    _Float16* Wg = (_Float16*)(ws + OFF_WG);
    _Float16* Wc = (_Float16*)(ws + OFF_WCONV);
    float* Cp    = (float*)(ws + OFF_CPART);   // aliases S (conv phase only)

    k_pack_gcn<<<(6 * NPAD * NPAD) / 256, 256, 0, stream>>>(wg[0], wg[1], wg[2], wg[3],
                                                            wg[4], wg[5], Wg);
    k_pack_conv<<<dim3(NPAD, 11, 19), 256, 0, stream>>>(cw, Wc);
    k_temp<<<(MGCN * IPAD) / 256, 256, 0, stream>>>(IF, x, week, hour, Xg);

    for (int l = 0; l < 3; ++l) {
        k_gemm<<<dim3(MGCN / 128, NFUSE / 128), 256, 0, stream>>>(
            Xg, Wg + (size_t)(2 * l) * NPAD * NPAD, S);
        k_bandact<<<MGCN, 256, 0, stream>>>(S, bg[2 * l], bg[2 * l + 1], Xg);
    }

    hipMemsetAsync(Cp, 0, (size_t)MCONV * NPAD * 4, stream);
    k_conv<<<dim3(MCONV / 256, CONV_SPLITS), 512, 0, stream>>>(Xg, Wc, Cp);

    k_reduce<<<dim3(32, 9, 11), 256, 0, stream>>>(Cp, cb, out);
}